// Round 2
// 1311.789 us; speedup vs baseline: 1.0244x; 1.0244x over previous
//
#include <hip/hip_runtime.h>

#define T_TOK 2048
#define HDIM  2048
#define NEXP  64
#define FDIM  512
#define KSEL  8
#define CAP   320
#define F2    1024

typedef __attribute__((ext_vector_type(8))) short bf16x8;
typedef __attribute__((ext_vector_type(4))) float f32x4;

__device__ __forceinline__ unsigned int pkbf(float a, float b) {
  unsigned int ua = __builtin_bit_cast(unsigned int, a);
  unsigned int ub = __builtin_bit_cast(unsigned int, b);
  return ((ua + 0x8000u) >> 16) | ((ub + 0x8000u) & 0xFFFF0000u);
}
__device__ __forceinline__ unsigned short f2bf(float a) {
  unsigned int ua = __builtin_bit_cast(unsigned int, a);
  return (unsigned short)((ua + 0x8000u) >> 16);
}
// single-instruction packed f32->bf16 (RNE): replaces 5 bit-ops per pair
__device__ __forceinline__ unsigned int cvtpk(float a, float b) {
  unsigned int r;
  asm("v_cvt_pk_bf16_f32 %0, %1, %2" : "=v"(r) : "v"(a), "v"(b));
  return r;
}

// Raw barrier WITHOUT the implicit fence's s_waitcnt vmcnt(0) drain:
// prefetch loads for tile k+2 stay in flight across the barrier (T3/T4).
// lgkmcnt(0) retires this wave's ds_writes before the barrier so other
// waves see the staged tile; sched_barrier(0) pins LDS-op ordering
// across the barrier at the scheduler level (rule 18 discipline).
__device__ __forceinline__ void pipe_barrier() {
  __builtin_amdgcn_sched_barrier(0);
  asm volatile("s_waitcnt lgkmcnt(0)" ::: "memory");
  __builtin_amdgcn_s_barrier();
  __builtin_amdgcn_sched_barrier(0);
}

// ---------------- x -> bf16 ----------------
__global__ void cvt_kernel(const float* __restrict__ x, unsigned short* __restrict__ xb) {
  int i = blockIdx.x * 256 + threadIdx.x;
  float4 v = reinterpret_cast<const float4*>(x)[i];
  uint2 o;
  o.x = pkbf(v.x, v.y);
  o.y = pkbf(v.z, v.w);
  reinterpret_cast<uint2*>(xb)[i] = o;
}

// ---------------- router: logits (f64 acc) -> softmax -> top-8 ----------------
__global__ __launch_bounds__(256) void router_kernel(
    const float* __restrict__ x, const float* __restrict__ rw,
    int* __restrict__ topi, float* __restrict__ topv, float* __restrict__ probsum) {
  __shared__ float ps[64];
  int tid = threadIdx.x;
  int wv = tid >> 6, lane = tid & 63;
  if (tid < 64) ps[tid] = 0.f;
  __syncthreads();
  int t = blockIdx.x * 4 + wv;
  const float* xrow = x + (long)t * HDIM;
  const float* wcol = rw + lane;
  double acc = 0.0;
#pragma unroll 8
  for (int h = 0; h < HDIM; h++)
    acc += (double)xrow[h] * (double)wcol[h * 64];
  float logit = (float)acc;
  float mx = logit;
  for (int off = 32; off; off >>= 1) mx = fmaxf(mx, __shfl_xor(mx, off));
  float ex = expf(logit - mx);
  float sm = ex;
  for (int off = 32; off; off >>= 1) sm += __shfl_xor(sm, off);
  float prob = ex / sm;
  atomicAdd(&ps[lane], prob);
  float p = prob;
  for (int k = 0; k < 8; k++) {
    float bv = p; int bi = lane;
    for (int off = 32; off; off >>= 1) {
      float ov = __shfl_xor(bv, off); int oi = __shfl_xor(bi, off);
      if (ov > bv || (ov == bv && oi < bi)) { bv = ov; bi = oi; }
    }
    if (lane == k) { topv[t * 8 + k] = bv; topi[t * 8 + k] = bi; }
    if (lane == bi) p = -1.f;
  }
  __syncthreads();
  if (tid < 64) atomicAdd(&probsum[tid], ps[tid]);
}

// ---------------- dispatch: exact k-major cumsum ranks ----------------
__global__ void rank_kernel(const int* __restrict__ topi, int* __restrict__ lrank,
                            int* __restrict__ hist) {
  __shared__ int ear[256];
  __shared__ unsigned short lr[256];
  int b = blockIdx.x, tid = threadIdx.x;
  int i = b * 256 + tid;
  int t = i & (T_TOK - 1), k = i >> 11;
  ear[tid] = topi[t * 8 + k];
  __syncthreads();
  if (tid < 64) {
    int c = 0;
    for (int j = 0; j < 256; j++)
      if (ear[j] == tid) { lr[j] = (unsigned short)c; c++; }
    hist[b * 64 + tid] = c;
  }
  __syncthreads();
  lrank[i] = lr[tid];
}

__global__ void scan_kernel(const int* __restrict__ hist, int* __restrict__ basetab,
                            int* __restrict__ cnt, const float* __restrict__ probsum,
                            float* __restrict__ aux_out) {
  int e = threadIdx.x;
  int run = 0;
  for (int b = 0; b < 64; b++) { basetab[b * 64 + e] = run; run += hist[b * 64 + e]; }
  cnt[e] = run;
  float v = (float)run * probsum[e];
  for (int off = 32; off; off >>= 1) v += __shfl_xor(v, off);
  if (e == 0) aux_out[0] = 64.0f * v / ((float)(KSEL * T_TOK) * (float)T_TOK);
}

__global__ void build_kernel(const int* __restrict__ topi, const float* __restrict__ topv,
                             const int* __restrict__ lrank, const int* __restrict__ basetab,
                             int* __restrict__ idx_tab, float* __restrict__ wt_tab) {
  int b = blockIdx.x, tid = threadIdx.x;
  int i = b * 256 + tid;
  int t = i & (T_TOK - 1), k = i >> 11;
  int e = topi[t * 8 + k];
  int slot = basetab[b * 64 + e] + lrank[i];
  if (slot < CAP) {
    idx_tab[e * CAP + slot] = t;
    wt_tab[e * CAP + slot] = topv[t * 8 + k];
  }
}

// ================= pipelined GEMMs: 64x128 tile, BK=32, double LDS buffer =================
// LDS row stride 34 shorts (17 words, odd -> conflict-free fragment reads)

struct RawGU { uint4 a; float2 g[8]; float2 u[8]; };
struct RawD  { uint4 a; float2 b[8]; };

// fused gate/up: h = relu(A@Bg)*(A@Bu)*w, bf16 out. A: bf16 [rows,2048]; Bg/Bu f32 [2048,N]
template <int N, bool GATHER, bool HASWT>
__global__ __launch_bounds__(256) void gemm_gate_up(
    const unsigned short* __restrict__ Ab,
    const int* __restrict__ idx, int idxStride,
    const float* __restrict__ Bg_, const float* __restrict__ Bu_, long bStride,
    const float* __restrict__ wt_,
    unsigned short* __restrict__ H_, long hStride, int ldH) {
  constexpr int SA = 34;
  __shared__ unsigned short As[2][64 * SA];
  __shared__ unsigned short Bgs[2][128 * SA];
  __shared__ unsigned short Bus[2][128 * SA];
  const int z = blockIdx.z;
  const int mt = blockIdx.y, nt = blockIdx.x;
  const int tid = threadIdx.x;
  const float* Bg = Bg_ + (long)z * bStride + nt * 128;
  const float* Bu = Bu_ + (long)z * bStride + nt * 128;
  const int* idxp = GATHER ? idx + (long)z * idxStride : nullptr;
  const float* wtp = HASWT ? wt_ + (long)z * idxStride : nullptr;
  unsigned short* Hout = H_ + (long)z * hStride;

  // staging roles
  const int arow = tid >> 2, achk = tid & 3;
  const int mg_a = mt * 64 + arow;
  long asrc = -1;
  {
    int s = GATHER ? idxp[mg_a] : mg_a;
    if (s >= 0) asrc = (long)s * HDIM + achk * 8;
  }
  const int n2 = (tid & 63) * 2, kh = tid >> 6;
  const float* bgp = Bg + (long)(kh * 8) * N + n2;
  const float* bup = Bu + (long)(kh * 8) * N + n2;

  // compute roles
  const int lane = tid & 63, r = lane & 15, quad = lane >> 4;
  const int wv = tid >> 6, wm = wv & 1, wn = wv >> 1;

  f32x4 accg[2][4] = {}, accu[2][4] = {};
  RawGU c0, c1;

  auto loadT = [&](int k0, RawGU& rg) {
    uint4 a = {0, 0, 0, 0};
    if (asrc >= 0) a = *reinterpret_cast<const uint4*>(Ab + asrc + k0);
    rg.a = a;
    const float* pg = bgp + (long)k0 * N;
    const float* pu = bup + (long)k0 * N;
#pragma unroll
    for (int j = 0; j < 8; j++) {
      rg.g[j] = *reinterpret_cast<const float2*>(pg + (long)j * N);
      rg.u[j] = *reinterpret_cast<const float2*>(pu + (long)j * N);
    }
  };
  auto storeT = [&](const RawGU& rg, int buf) {
    *reinterpret_cast<uint4*>(&As[buf][arow * SA + achk * 8]) = rg.a;
    uint4 w;
    w.x = cvtpk(rg.g[0].x, rg.g[1].x); w.y = cvtpk(rg.g[2].x, rg.g[3].x);
    w.z = cvtpk(rg.g[4].x, rg.g[5].x); w.w = cvtpk(rg.g[6].x, rg.g[7].x);
    *reinterpret_cast<uint4*>(&Bgs[buf][n2 * SA + kh * 8]) = w;
    w.x = cvtpk(rg.g[0].y, rg.g[1].y); w.y = cvtpk(rg.g[2].y, rg.g[3].y);
    w.z = cvtpk(rg.g[4].y, rg.g[5].y); w.w = cvtpk(rg.g[6].y, rg.g[7].y);
    *reinterpret_cast<uint4*>(&Bgs[buf][(n2 + 1) * SA + kh * 8]) = w;
    w.x = cvtpk(rg.u[0].x, rg.u[1].x); w.y = cvtpk(rg.u[2].x, rg.u[3].x);
    w.z = cvtpk(rg.u[4].x, rg.u[5].x); w.w = cvtpk(rg.u[6].x, rg.u[7].x);
    *reinterpret_cast<uint4*>(&Bus[buf][n2 * SA + kh * 8]) = w;
    w.x = cvtpk(rg.u[0].y, rg.u[1].y); w.y = cvtpk(rg.u[2].y, rg.u[3].y);
    w.z = cvtpk(rg.u[4].y, rg.u[5].y); w.w = cvtpk(rg.u[6].y, rg.u[7].y);
    *reinterpret_cast<uint4*>(&Bus[buf][(n2 + 1) * SA + kh * 8]) = w;
  };
  auto compT = [&](int buf) {
    bf16x8 a0 = *reinterpret_cast<const bf16x8*>(&As[buf][(wm * 32 + r) * SA + quad * 8]);
    bf16x8 a1 = *reinterpret_cast<const bf16x8*>(&As[buf][(wm * 32 + 16 + r) * SA + quad * 8]);
#pragma unroll
    for (int bn = 0; bn < 4; bn++) {
      bf16x8 b = *reinterpret_cast<const bf16x8*>(&Bgs[buf][(wn * 64 + bn * 16 + r) * SA + quad * 8]);
      accg[0][bn] = __builtin_amdgcn_mfma_f32_16x16x32_bf16(a0, b, accg[0][bn], 0, 0, 0);
      accg[1][bn] = __builtin_amdgcn_mfma_f32_16x16x32_bf16(a1, b, accg[1][bn], 0, 0, 0);
    }
#pragma unroll
    for (int bn = 0; bn < 4; bn++) {
      bf16x8 b = *reinterpret_cast<const bf16x8*>(&Bus[buf][(wn * 64 + bn * 16 + r) * SA + quad * 8]);
      accu[0][bn] = __builtin_amdgcn_mfma_f32_16x16x32_bf16(a0, b, accu[0][bn], 0, 0, 0);
      accu[1][bn] = __builtin_amdgcn_mfma_f32_16x16x32_bf16(a1, b, accu[1][bn], 0, 0, 0);
    }
  };

  loadT(0, c0);
  storeT(c0, 0);
  loadT(32, c0);
  pipe_barrier();
  constexpr int NK = HDIM / 32;  // 64
#pragma unroll 1
  for (int kt = 0; kt < NK; kt += 2) {
    if (kt + 2 < NK) loadT((kt + 2) * 32, c1);
    compT(0);
    storeT(c0, 1);
    pipe_barrier();
    if (kt + 3 < NK) loadT((kt + 3) * 32, c0);
    compT(1);
    if (kt + 2 < NK) storeT(c1, 0);
    pipe_barrier();
  }

#pragma unroll
  for (int bm = 0; bm < 2; bm++)
#pragma unroll
    for (int i = 0; i < 4; i++) {
      int mg = mt * 64 + wm * 32 + bm * 16 + quad * 4 + i;
      float w = HASWT ? wtp[mg] : 1.0f;
#pragma unroll
      for (int bn = 0; bn < 4; bn++) {
        int n = nt * 128 + wn * 64 + bn * 16 + r;
        float g = accg[bm][bn][i], u = accu[bm][bn][i];
        Hout[(long)mg * ldH + n] = f2bf(fmaxf(g, 0.f) * u * w);
      }
    }
}

// down GEMM (N=2048): out += A @ B, scatter or direct
template <int KD, int LDA, bool SCATTER>
__global__ __launch_bounds__(256) void gemm_down(
    const unsigned short* __restrict__ Ab, long aStride,
    const float* __restrict__ B_, long bStride,
    const int* __restrict__ idx, int idxStride,
    float* __restrict__ out) {
  constexpr int SA = 34;
  constexpr int N = HDIM;
  __shared__ unsigned short As[2][64 * SA];
  __shared__ unsigned short Bs[2][128 * SA];
  const int z = blockIdx.z;
  const int mt = blockIdx.y, nt = blockIdx.x;
  const int tid = threadIdx.x;
  const unsigned short* A = Ab + (long)z * aStride;
  const float* B = B_ + (long)z * bStride + nt * 128;
  const int* idxp = SCATTER ? idx + (long)z * idxStride : nullptr;

  const int arow = tid >> 2, achk = tid & 3;
  const long asrc = (long)(mt * 64 + arow) * LDA + achk * 8;
  const int n2 = (tid & 63) * 2, kh = tid >> 6;
  const float* bp = B + (long)(kh * 8) * N + n2;

  const int lane = tid & 63, r = lane & 15, quad = lane >> 4;
  const int wv = tid >> 6, wm = wv & 1, wn = wv >> 1;

  f32x4 acc[2][4] = {};
  RawD c0, c1;

  auto loadT = [&](int k0, RawD& rg) {
    rg.a = *reinterpret_cast<const uint4*>(A + asrc + k0);
    const float* p = bp + (long)k0 * N;
#pragma unroll
    for (int j = 0; j < 8; j++)
      rg.b[j] = *reinterpret_cast<const float2*>(p + (long)j * N);
  };
  auto storeT = [&](const RawD& rg, int buf) {
    *reinterpret_cast<uint4*>(&As[buf][arow * SA + achk * 8]) = rg.a;
    uint4 w;
    w.x = cvtpk(rg.b[0].x, rg.b[1].x); w.y = cvtpk(rg.b[2].x, rg.b[3].x);
    w.z = cvtpk(rg.b[4].x, rg.b[5].x); w.w = cvtpk(rg.b[6].x, rg.b[7].x);
    *reinterpret_cast<uint4*>(&Bs[buf][n2 * SA + kh * 8]) = w;
    w.x = cvtpk(rg.b[0].y, rg.b[1].y); w.y = cvtpk(rg.b[2].y, rg.b[3].y);
    w.z = cvtpk(rg.b[4].y, rg.b[5].y); w.w = cvtpk(rg.b[6].y, rg.b[7].y);
    *reinterpret_cast<uint4*>(&Bs[buf][(n2 + 1) * SA + kh * 8]) = w;
  };
  auto compT = [&](int buf) {
    bf16x8 a0 = *reinterpret_cast<const bf16x8*>(&As[buf][(wm * 32 + r) * SA + quad * 8]);
    bf16x8 a1 = *reinterpret_cast<const bf16x8*>(&As[buf][(wm * 32 + 16 + r) * SA + quad * 8]);
#pragma unroll
    for (int bn = 0; bn < 4; bn++) {
      bf16x8 b = *reinterpret_cast<const bf16x8*>(&Bs[buf][(wn * 64 + bn * 16 + r) * SA + quad * 8]);
      acc[0][bn] = __builtin_amdgcn_mfma_f32_16x16x32_bf16(a0, b, acc[0][bn], 0, 0, 0);
      acc[1][bn] = __builtin_amdgcn_mfma_f32_16x16x32_bf16(a1, b, acc[1][bn], 0, 0, 0);
    }
  };

  loadT(0, c0);
  storeT(c0, 0);
  loadT(32, c0);
  pipe_barrier();
  constexpr int NK = KD / 32;
#pragma unroll 1
  for (int kt = 0; kt < NK; kt += 2) {
    if (kt + 2 < NK) loadT((kt + 2) * 32, c1);
    compT(0);
    storeT(c0, 1);
    pipe_barrier();
    if (kt + 3 < NK) loadT((kt + 3) * 32, c0);
    compT(1);
    if (kt + 2 < NK) storeT(c1, 0);
    pipe_barrier();
  }

#pragma unroll
  for (int bm = 0; bm < 2; bm++)
#pragma unroll
    for (int i = 0; i < 4; i++) {
      int mg = mt * 64 + wm * 32 + bm * 16 + quad * 4 + i;
      if (SCATTER) {
        int tok = idxp[mg];
        if (tok >= 0) {
          float* orow = out + (long)tok * HDIM + nt * 128 + wn * 64 + r;
#pragma unroll
          for (int bn = 0; bn < 4; bn++) atomicAdd(orow + bn * 16, acc[bm][bn][i]);
        }
      } else {
        float* orow = out + (long)mg * HDIM + nt * 128 + wn * 64 + r;
#pragma unroll
        for (int bn = 0; bn < 4; bn++) orow[bn * 16] += acc[bm][bn][i];
      }
    }
}

extern "C" void kernel_launch(void* const* d_in, const int* in_sizes, int n_in,
                              void* d_out, int out_size, void* d_ws, size_t ws_size,
                              hipStream_t stream) {
  const float* x   = (const float*)d_in[0];
  const float* rw  = (const float*)d_in[1];
  const float* wg  = (const float*)d_in[2];
  const float* wu  = (const float*)d_in[3];
  const float* wd  = (const float*)d_in[4];
  const float* swg = (const float*)d_in[5];
  const float* swu = (const float*)d_in[6];
  const float* swd = (const float*)d_in[7];
  float* out = (float*)d_out;

  char* ws = (char*)d_ws;
  size_t off = 0;
  auto alloc = [&](size_t bytes) -> char* {
    char* p = ws + off;
    off = (off + bytes + 255) & ~(size_t)255;
    return p;
  };
  unsigned short* xbf   = (unsigned short*)alloc((size_t)T_TOK * HDIM * 2);
  unsigned short* hbuf  = (unsigned short*)alloc((size_t)NEXP * CAP * FDIM * 2);
  unsigned short* hsbuf = (unsigned short*)alloc((size_t)T_TOK * 2 * F2 * 2);  // [T, 2*F2] interleaved
  int*   topi    = (int*)alloc(T_TOK * KSEL * 4);
  float* topv    = (float*)alloc(T_TOK * KSEL * 4);
  int*   lrank   = (int*)alloc(T_TOK * KSEL * 4);
  int*   hist    = (int*)alloc(64 * 64 * 4);
  int*   basetab = (int*)alloc(64 * 64 * 4);
  int*   cnt     = (int*)alloc(64 * 4);
  float* probsum = (float*)alloc(64 * 4);
  int*   idx_tab = (int*)alloc(NEXP * CAP * 4);
  float* wt_tab  = (float*)alloc(NEXP * CAP * 4);

  hipMemsetAsync(out, 0, (size_t)T_TOK * HDIM * 4, stream);
  hipMemsetAsync(probsum, 0, 64 * 4, stream);
  hipMemsetAsync(idx_tab, 0xFF, NEXP * CAP * 4, stream);
  hipMemsetAsync(wt_tab, 0, NEXP * CAP * 4, stream);

  cvt_kernel<<<T_TOK * HDIM / 4 / 256, 256, 0, stream>>>(x, xbf);
  router_kernel<<<T_TOK / 4, 256, 0, stream>>>(x, rw, topi, topv, probsum);
  rank_kernel<<<64, 256, 0, stream>>>(topi, lrank, hist);
  scan_kernel<<<1, 64, 0, stream>>>(hist, basetab, cnt, probsum, out + (size_t)T_TOK * HDIM);
  build_kernel<<<64, 256, 0, stream>>>(topi, topv, lrank, basetab, idx_tab, wt_tab);

  // routed gate/up: [E] x [320,512] = gather(x) @ wg/wu (weight folded into h)
  gemm_gate_up<FDIM, true, true><<<dim3(FDIM / 128, CAP / 64, NEXP), 256, 0, stream>>>(
      xbf, idx_tab, CAP, wg, wu, (long)HDIM * FDIM, wt_tab, hbuf, (long)CAP * FDIM, FDIM);
  // shared gate/up: [2] x [2048,1024] -> interleaved hsbuf [T, 2048]
  gemm_gate_up<F2, false, false><<<dim3(F2 / 128, T_TOK / 64, 2), 256, 0, stream>>>(
      xbf, nullptr, 0, swg, swu, (long)HDIM * F2, nullptr, hsbuf, (long)F2, 2 * F2);
  // routed down + scatter-add combine: [E] x [320,2048] @ wd
  gemm_down<FDIM, FDIM, true><<<dim3(HDIM / 128, CAP / 64, NEXP), 256, 0, stream>>>(
      hbuf, (long)CAP * FDIM, wd, (long)FDIM * HDIM, idx_tab, CAP, out);
  // shared down (both experts merged, K=2048): out += hsbuf @ sw_d_flat
  gemm_down<2 * F2, 2 * F2, false><<<dim3(HDIM / 128, T_TOK / 64, 1), 256, 0, stream>>>(
      hsbuf, 0L, swd, 0L, nullptr, 0, out);
}